// Round 2
// baseline (662.094 us; speedup 1.0000x reference)
//
#include <hip/hip_runtime.h>
#include <hip/hip_bf16.h>

#define NN   50000
#define E2   400000

__device__ __forceinline__ float eluf(float x) { return x > 0.0f ? x : expm1f(x); }
__device__ __forceinline__ float sigmoidf(float x) { return 1.0f / (1.0f + expf(-x)); }

// ---------------- lin1: xc = elu(x @ W1^T + b1), [NN,128]x[128,96] -> f32 [NN,96]
__global__ __launch_bounds__(256) void k_lin1(const float* __restrict__ x,
                                              const float* __restrict__ W1,
                                              const float* __restrict__ b1,
                                              float* __restrict__ xc) {
    __shared__ float w1s[96 * 129];   // pad 129 -> conflict-free column walk
    __shared__ float xs[8][128];
    int tid = threadIdx.x;
    for (int i = tid; i < 96 * 128; i += 256)
        w1s[(i / 128) * 129 + (i % 128)] = W1[i];
    int n0 = blockIdx.x * 8;
    for (int i = tid; i < 8 * 128; i += 256) {
        int n = n0 + i / 128;
        xs[i / 128][i % 128] = (n < NN) ? x[n * 128 + (i % 128)] : 0.0f;
    }
    __syncthreads();
    int ln = tid >> 5, c = tid & 31;
    int n = n0 + ln;
    if (n >= NN) return;
    for (int jj = 0; jj < 3; ++jj) {
        int j = jj * 32 + c;
        float acc = b1[j];
        const float* wr = &w1s[j * 129];
        const float* xr = xs[ln];
#pragma unroll 8
        for (int k = 0; k < 128; ++k) acc = fmaf(xr[k], wr[k], acc);
        xc[n * 96 + j] = eluf(acc);
    }
}

// ---------------- spectral norm of W_left[l] (3x3) and W_right[l] (32x32), 20 power iters
__global__ __launch_bounds__(64) void k_spectral(const float* __restrict__ Wl_in,
                                                 const float* __restrict__ Wr_in,
                                                 float* __restrict__ Wl_out,
                                                 float* __restrict__ Wr_out) {
    int l = blockIdx.x, t = threadIdx.x;
    __shared__ float W[32 * 33];
    __shared__ float us[32], vs[32], tmp[32];
    __shared__ float scal;
    for (int i = t; i < 1024; i += 64) W[(i >> 5) * 33 + (i & 31)] = Wr_in[l * 1024 + i];
    if (t < 32) us[t] = 0.17677669529663688f;  // 1/sqrt(32)
    __syncthreads();
    for (int it = 0; it < 20; ++it) {
        if (t < 32) { float a = 0; for (int r = 0; r < 32; ++r) a = fmaf(W[r * 33 + t], us[r], a); tmp[t] = a; }
        __syncthreads();
        if (t == 0) { float s = 0; for (int c = 0; c < 32; ++c) s += tmp[c] * tmp[c]; scal = 1.0f / (sqrtf(s) + 1e-12f); }
        __syncthreads();
        if (t < 32) vs[t] = tmp[t] * scal;
        __syncthreads();
        if (t < 32) { float a = 0; for (int c = 0; c < 32; ++c) a = fmaf(W[t * 33 + c], vs[c], a); tmp[t] = a; }
        __syncthreads();
        if (t == 0) { float s = 0; for (int r = 0; r < 32; ++r) s += tmp[r] * tmp[r]; scal = 1.0f / (sqrtf(s) + 1e-12f); }
        __syncthreads();
        if (t < 32) us[t] = tmp[t] * scal;
        __syncthreads();
    }
    if (t < 32) { float a = 0; for (int r = 0; r < 32; ++r) a = fmaf(W[r * 33 + t], us[r], a); tmp[t] = a; }
    __syncthreads();
    if (t == 0) {
        float s = 0; for (int c = 0; c < 32; ++c) s += tmp[c] * tmp[c];
        float sigma = s / (sqrtf(s) + 1e-12f);
        scal = 1.0f / sigma;
    }
    __syncthreads();
    for (int i = t; i < 1024; i += 64) Wr_out[l * 1024 + i] = W[(i >> 5) * 33 + (i & 31)] * scal;

    if (t == 0) {  // W_left 3x3, serial
        float M[9];
        for (int i = 0; i < 9; ++i) M[i] = Wl_in[l * 9 + i];
        float u[3] = {0.5773502691896258f, 0.5773502691896258f, 0.5773502691896258f};
        float v[3], u2[3];
        for (int it = 0; it < 20; ++it) {
            float s = 0;
            for (int c = 0; c < 3; ++c) { v[c] = M[c] * u[0] + M[3 + c] * u[1] + M[6 + c] * u[2]; s += v[c] * v[c]; }
            float inv = 1.0f / (sqrtf(s) + 1e-12f);
            for (int c = 0; c < 3; ++c) v[c] *= inv;
            s = 0;
            for (int r = 0; r < 3; ++r) { u2[r] = M[r * 3] * v[0] + M[r * 3 + 1] * v[1] + M[r * 3 + 2] * v[2]; s += u2[r] * u2[r]; }
            inv = 1.0f / (sqrtf(s) + 1e-12f);
            for (int r = 0; r < 3; ++r) u[r] = u2[r] * inv;
        }
        float s = 0;
        for (int c = 0; c < 3; ++c) { v[c] = M[c] * u[0] + M[3 + c] * u[1] + M[6 + c] * u[2]; s += v[c] * v[c]; }
        float sigma = s / (sqrtf(s) + 1e-12f);
        float inv = 1.0f / sigma;
        for (int i = 0; i < 9; ++i) Wl_out[l * 9 + i] = M[i] * inv;
    }
}

// ---------------- per-node projections for sheaf/weight MLP (linearity split)
__global__ __launch_bounds__(256) void k_nodeproj(const float* __restrict__ xc,
                                                  const float* __restrict__ Wsh,
                                                  const float* __restrict__ Wwt,
                                                  int layer,
                                                  float* __restrict__ aR, float* __restrict__ aC,
                                                  float* __restrict__ wR, float* __restrict__ wC) {
    __shared__ float ws1[192], wt[192];
    int tid = threadIdx.x;
    if (tid < 192) {
        ws1[tid] = Wsh[(layer * 3 + 1) * 192 + tid];  // only row 1 of W_sheaf survives the Cayley map (D=2)
        wt[tid]  = Wwt[layer * 192 + tid];
    }
    __syncthreads();
    int lane = tid & 63, w = tid >> 6;
    int n = blockIdx.x * 4 + w;
    if (n >= NN) return;
    float a1 = 0, a2 = 0, a3 = 0, a4 = 0;
    for (int k = lane; k < 96; k += 64) {
        float xv = xc[n * 96 + k];
        a1 = fmaf(xv, ws1[k], a1);
        a2 = fmaf(xv, ws1[96 + k], a2);
        a3 = fmaf(xv, wt[k], a3);
        a4 = fmaf(xv, wt[96 + k], a4);
    }
    for (int off = 32; off; off >>= 1) {
        a1 += __shfl_xor(a1, off);
        a2 += __shfl_xor(a2, off);
        a3 += __shfl_xor(a3, off);
        a4 += __shfl_xor(a4, off);
    }
    if (lane == 0) { aR[n] = a1; aC[n] = a2; wR[n] = a3; wC[n] = a4; }
}

// ---------------- degree accumulation: deg[row] += w^2
__global__ __launch_bounds__(256) void k_deg(const int* __restrict__ row, const int* __restrict__ col,
                                             const float* __restrict__ wR, const float* __restrict__ wC,
                                             float* __restrict__ deg) {
    int e = blockIdx.x * 256 + threadIdx.x;
    if (e >= E2) return;
    int u = row[e], v = col[e];
    float wd_e = sigmoidf(wR[u] + wC[v]);
    float wd_r = sigmoidf(wR[v] + wC[u]);  // reverse-edge wdir, recomputed locally
    float w = wd_e * wd_r;
    atomicAdd(&deg[u], w * w);
}

__global__ __launch_bounds__(256) void k_dinv(const float* __restrict__ deg, float* __restrict__ dinv) {
    int n = blockIdx.x * 256 + threadIdx.x;
    if (n >= NN) return;
    float d = deg[n];
    dinv[n] = d > 0.0f ? rsqrtf(fmaxf(d, 1e-30f)) : 0.0f;
}

// ---------------- y[n,f,c] = sum_g Wl[f,g] * sum_h xc[n,g,h] * Wr[c,h]
__global__ __launch_bounds__(192) void k_y(const float* __restrict__ xc,
                                           const float* __restrict__ Wl,
                                           const float* __restrict__ Wr,
                                           float* __restrict__ y) {
    __shared__ float wrs[32 * 33];
    __shared__ float wls[9];
    __shared__ float xcs[2][96];
    __shared__ float ts[2][3][32];
    int tid = threadIdx.x;
    for (int i = tid; i < 1024; i += 192) wrs[(i >> 5) * 33 + (i & 31)] = Wr[i];
    if (tid < 9) wls[tid] = Wl[tid];
    int n0 = blockIdx.x * 2;
    {
        int n = n0 + tid / 96;
        if (n < NN) xcs[tid / 96][tid % 96] = xc[n * 96 + tid % 96];
    }
    __syncthreads();
    int node = tid / 96, r = tid % 96, g = r >> 5, c = r & 31;
    int n = n0 + node;
    if (n < NN) {
        float acc = 0;
        const float* xr = &xcs[node][g * 32];
        const float* wr = &wrs[c * 33];
#pragma unroll
        for (int h = 0; h < 32; ++h) acc = fmaf(xr[h], wr[h], acc);
        ts[node][g][c] = acc;
    }
    __syncthreads();
    if (n < NN) {
        float o = wls[g * 3 + 0] * ts[node][0][c] + wls[g * 3 + 1] * ts[node][1][c] + wls[g * 3 + 2] * ts[node][2][c];
        y[n * 96 + g * 32 + c] = o;
    }
}

// ---------------- edge transport + scatter: agg[u] += cnorm * T(e) @ y[v]
__global__ __launch_bounds__(256) void k_scatter(const int* __restrict__ row, const int* __restrict__ col,
                                                 const float* __restrict__ aR, const float* __restrict__ aC,
                                                 const float* __restrict__ wR, const float* __restrict__ wC,
                                                 const float* __restrict__ dinv,
                                                 const float* __restrict__ y, float* __restrict__ agg) {
    int tid = threadIdx.x;
    int e = blockIdx.x * 8 + (tid >> 5);
    int h = tid & 31;
    if (e >= E2) return;
    int u = row[e], v = col[e];
    float a_e = tanhf(aR[u] + aC[v]);
    float a_r = tanhf(aR[v] + aC[u]);
    float wd_e = sigmoidf(wR[u] + wC[v]);
    float wd_r = sigmoidf(wR[v] + wC[u]);
    float w = wd_e * wd_r;
    float cn = w * w * dinv[u] * dinv[v];
    float ie = 1.0f / (1.0f + a_e * a_e), ir = 1.0f / (1.0f + a_r * a_r);
    float ce = (1.0f - a_e * a_e) * ie, se = 2.0f * a_e * ie;
    float cr = (1.0f - a_r * a_r) * ir, sr = 2.0f * a_r * ir;
    float C = ce * cr + se * sr;           // T = Q_e^T Q_rev (2x2 rotation)
    float S = ce * sr - se * cr;
    float y0 = y[v * 96 + h], y1 = y[v * 96 + 32 + h], y2 = y[v * 96 + 64 + h];
    atomicAdd(&agg[u * 96 + h],      cn * (C * y0 - S * y1));
    atomicAdd(&agg[u * 96 + 32 + h], cn * (S * y0 + C * y1));
    atomicAdd(&agg[u * 96 + 64 + h], cn * y2);
}

// ---------------- residual update: xc = coeff*xc - elu(diag*y - agg)
__global__ __launch_bounds__(256) void k_update(const float* __restrict__ y, const float* __restrict__ agg,
                                                const float* __restrict__ deg, const float* __restrict__ eps,
                                                int layer, float* __restrict__ xc) {
    int i = blockIdx.x * 256 + threadIdx.x;
    if (i >= NN * 96) return;
    int n = i / 96;
    int f = (i % 96) >> 5;
    float diag = deg[n] > 0.0f ? 1.0f : 0.0f;
    float z = eluf(diag * y[i] - agg[i]);
    float coeff = 1.0f + tanhf(eps[layer * 3 + f]);
    xc[i] = coeff * xc[i] - z;
}

// ---------------- lin2: out = xc @ W2^T + b2 -> f32 [NN,32]
__global__ __launch_bounds__(256) void k_lin2(const float* __restrict__ xc, const float* __restrict__ W2,
                                              const float* __restrict__ bias2, float* __restrict__ out) {
    __shared__ float w2s[32 * 97];
    __shared__ float xcs[8][96];
    int tid = threadIdx.x;
    for (int i = tid; i < 32 * 96; i += 256) w2s[(i / 96) * 97 + (i % 96)] = W2[i];
    int n0 = blockIdx.x * 8;
    for (int i = tid; i < 8 * 96; i += 256) {
        int n = n0 + i / 96;
        if (n < NN) xcs[i / 96][i % 96] = xc[n * 96 + i % 96];
    }
    __syncthreads();
    int ln = tid >> 5, c = tid & 31;
    int n = n0 + ln;
    if (n >= NN) return;
    float acc = bias2[c];
    const float* xr = xcs[ln];
    const float* wr = &w2s[c * 97];
#pragma unroll 8
    for (int k = 0; k < 96; ++k) acc = fmaf(xr[k], wr[k], acc);
    out[n * 32 + c] = acc;
}

extern "C" void kernel_launch(void* const* d_in, const int* in_sizes, int n_in,
                              void* d_out, int out_size, void* d_ws, size_t ws_size,
                              hipStream_t stream) {
    const float* x     = (const float*)d_in[0];
    const int*   ei    = (const int*)d_in[1];
    const float* W1    = (const float*)d_in[2];
    const float* b1    = (const float*)d_in[3];
    const float* W2    = (const float*)d_in[4];
    const float* bias2 = (const float*)d_in[5];
    const float* Wl_in = (const float*)d_in[6];
    const float* Wr_in = (const float*)d_in[7];
    const float* eps   = (const float*)d_in[8];
    const float* Wsh   = (const float*)d_in[9];
    const float* Wwt   = (const float*)d_in[10];
    float* out = (float*)d_out;
    const int* row = ei;        // edge_index[0]
    const int* col = ei + E2;   // edge_index[1]

    float* p    = (float*)d_ws;
    float* xc   = p; p += NN * 96;
    float* y    = p; p += NN * 96;
    float* agg  = p; p += NN * 96;
    float* aR   = p; p += NN;
    float* aC   = p; p += NN;
    float* wRp  = p; p += NN;
    float* wCp  = p; p += NN;
    float* deg  = p; p += NN;
    float* dinv = p; p += NN;
    float* Wl_n = p; p += 32;
    float* Wr_n = p; p += 2048;

    k_lin1<<<(NN + 7) / 8, 256, 0, stream>>>(x, W1, b1, xc);
    k_spectral<<<2, 64, 0, stream>>>(Wl_in, Wr_in, Wl_n, Wr_n);
    for (int l = 0; l < 2; ++l) {
        k_nodeproj<<<(NN + 3) / 4, 256, 0, stream>>>(xc, Wsh, Wwt, l, aR, aC, wRp, wCp);
        hipMemsetAsync(deg, 0, NN * sizeof(float), stream);
        hipMemsetAsync(agg, 0, NN * 96 * sizeof(float), stream);
        k_deg<<<(E2 + 255) / 256, 256, 0, stream>>>(row, col, wRp, wCp, deg);
        k_dinv<<<(NN + 255) / 256, 256, 0, stream>>>(deg, dinv);
        k_y<<<NN / 2, 192, 0, stream>>>(xc, Wl_n + l * 9, Wr_n + l * 1024, y);
        k_scatter<<<(E2 + 7) / 8, 256, 0, stream>>>(row, col, aR, aC, wRp, wCp, dinv, y, agg);
        k_update<<<(NN * 96 + 255) / 256, 256, 0, stream>>>(y, agg, deg, eps, l, xc);
    }
    k_lin2<<<(NN + 7) / 8, 256, 0, stream>>>(xc, W2, bias2, out);
}

// Round 3
// 499.385 us; speedup vs baseline: 1.3258x; 1.3258x over previous
//
#include <hip/hip_runtime.h>
#include <hip/hip_bf16.h>

#define NN   50000
#define E2   400000

__device__ __forceinline__ float eluf(float x) { return x > 0.0f ? x : expm1f(x); }
__device__ __forceinline__ float sigmoidf(float x) { return 1.0f / (1.0f + expf(-x)); }

// ---------------- lin1: xc = elu(x @ W1^T + b1), [NN,128]x[128,96] -> f32 [NN,96]
__global__ __launch_bounds__(256) void k_lin1(const float* __restrict__ x,
                                              const float* __restrict__ W1,
                                              const float* __restrict__ b1,
                                              float* __restrict__ xc) {
    __shared__ float w1s[96 * 129];
    __shared__ float xs[8][128];
    int tid = threadIdx.x;
    for (int i = tid; i < 96 * 128; i += 256)
        w1s[(i / 128) * 129 + (i % 128)] = W1[i];
    int n0 = blockIdx.x * 8;
    for (int i = tid; i < 8 * 128; i += 256) {
        int n = n0 + i / 128;
        xs[i / 128][i % 128] = (n < NN) ? x[n * 128 + (i % 128)] : 0.0f;
    }
    __syncthreads();
    int ln = tid >> 5, c = tid & 31;
    int n = n0 + ln;
    if (n >= NN) return;
    for (int jj = 0; jj < 3; ++jj) {
        int j = jj * 32 + c;
        float acc = b1[j];
        const float* wr = &w1s[j * 129];
        const float* xr = xs[ln];
#pragma unroll 8
        for (int k = 0; k < 128; ++k) acc = fmaf(xr[k], wr[k], acc);
        xc[n * 96 + j] = eluf(acc);
    }
}

// ---------------- spectral norm of W_left[l] (3x3) and W_right[l] (32x32)
__global__ __launch_bounds__(64) void k_spectral(const float* __restrict__ Wl_in,
                                                 const float* __restrict__ Wr_in,
                                                 float* __restrict__ Wl_out,
                                                 float* __restrict__ Wr_out) {
    int l = blockIdx.x, t = threadIdx.x;
    __shared__ float W[32 * 33];
    __shared__ float us[32], vs[32], tmp[32];
    __shared__ float scal;
    for (int i = t; i < 1024; i += 64) W[(i >> 5) * 33 + (i & 31)] = Wr_in[l * 1024 + i];
    if (t < 32) us[t] = 0.17677669529663688f;
    __syncthreads();
    for (int it = 0; it < 20; ++it) {
        if (t < 32) { float a = 0; for (int r = 0; r < 32; ++r) a = fmaf(W[r * 33 + t], us[r], a); tmp[t] = a; }
        __syncthreads();
        if (t == 0) { float s = 0; for (int c = 0; c < 32; ++c) s += tmp[c] * tmp[c]; scal = 1.0f / (sqrtf(s) + 1e-12f); }
        __syncthreads();
        if (t < 32) vs[t] = tmp[t] * scal;
        __syncthreads();
        if (t < 32) { float a = 0; for (int c = 0; c < 32; ++c) a = fmaf(W[t * 33 + c], vs[c], a); tmp[t] = a; }
        __syncthreads();
        if (t == 0) { float s = 0; for (int r = 0; r < 32; ++r) s += tmp[r] * tmp[r]; scal = 1.0f / (sqrtf(s) + 1e-12f); }
        __syncthreads();
        if (t < 32) us[t] = tmp[t] * scal;
        __syncthreads();
    }
    if (t < 32) { float a = 0; for (int r = 0; r < 32; ++r) a = fmaf(W[r * 33 + t], us[r], a); tmp[t] = a; }
    __syncthreads();
    if (t == 0) {
        float s = 0; for (int c = 0; c < 32; ++c) s += tmp[c] * tmp[c];
        scal = (sqrtf(s) + 1e-12f) / s;  // 1/sigma
    }
    __syncthreads();
    for (int i = t; i < 1024; i += 64) Wr_out[l * 1024 + i] = W[(i >> 5) * 33 + (i & 31)] * scal;

    if (t == 0) {
        float M[9];
        for (int i = 0; i < 9; ++i) M[i] = Wl_in[l * 9 + i];
        float u[3] = {0.5773502691896258f, 0.5773502691896258f, 0.5773502691896258f};
        float v[3], u2[3];
        for (int it = 0; it < 20; ++it) {
            float s = 0;
            for (int c = 0; c < 3; ++c) { v[c] = M[c] * u[0] + M[3 + c] * u[1] + M[6 + c] * u[2]; s += v[c] * v[c]; }
            float inv = 1.0f / (sqrtf(s) + 1e-12f);
            for (int c = 0; c < 3; ++c) v[c] *= inv;
            s = 0;
            for (int r = 0; r < 3; ++r) { u2[r] = M[r * 3] * v[0] + M[r * 3 + 1] * v[1] + M[r * 3 + 2] * v[2]; s += u2[r] * u2[r]; }
            inv = 1.0f / (sqrtf(s) + 1e-12f);
            for (int r = 0; r < 3; ++r) u[r] = u2[r] * inv;
        }
        float s = 0;
        for (int c = 0; c < 3; ++c) { v[c] = M[c] * u[0] + M[3 + c] * u[1] + M[6 + c] * u[2]; s += v[c] * v[c]; }
        float inv = (sqrtf(s) + 1e-12f) / s;
        for (int i = 0; i < 9; ++i) Wl_out[l * 9 + i] = M[i] * inv;
    }
}

// ---------------- CSR build --------------------------------------------------
__global__ __launch_bounds__(256) void k_hist(const int* __restrict__ row, int* __restrict__ cnt) {
    int e = blockIdx.x * 256 + threadIdx.x;
    if (e < E2) atomicAdd(&cnt[row[e]], 1);
}
__global__ __launch_bounds__(256) void k_scan1(const int* __restrict__ cnt, int* __restrict__ start,
                                               int* __restrict__ bsum) {
    __shared__ int s[256];
    int b = blockIdx.x, t = threadIdx.x;
    int i = b * 256 + t;
    int v = (i < NN) ? cnt[i] : 0;
    s[t] = v;
    __syncthreads();
    for (int off = 1; off < 256; off <<= 1) {
        int add = (t >= off) ? s[t - off] : 0;
        __syncthreads();
        s[t] += add;
        __syncthreads();
    }
    if (i < NN) start[i] = s[t] - v;     // exclusive, pre-offset
    if (t == 255) bsum[b] = s[t];
}
__global__ __launch_bounds__(256) void k_scan2(const int* __restrict__ bsum, int* __restrict__ bofs,
                                               int nb) {
    __shared__ int s[256];
    int t = threadIdx.x;
    int v = (t < nb) ? bsum[t] : 0;
    s[t] = v;
    __syncthreads();
    for (int off = 1; off < 256; off <<= 1) {
        int add = (t >= off) ? s[t - off] : 0;
        __syncthreads();
        s[t] += add;
        __syncthreads();
    }
    if (t < nb) bofs[t] = s[t] - v;
}
__global__ __launch_bounds__(256) void k_scan3(int* __restrict__ start, const int* __restrict__ bofs) {
    int i = blockIdx.x * 256 + threadIdx.x;
    if (i < NN) start[i] += bofs[i >> 8];
}
__global__ __launch_bounds__(256) void k_fill(const int* __restrict__ row, const int* __restrict__ start,
                                              int* __restrict__ fill, int* __restrict__ csr) {
    int e = blockIdx.x * 256 + threadIdx.x;
    if (e >= E2) return;
    int u = row[e];
    int slot = start[u] + atomicAdd(&fill[u], 1);
    csr[slot] = e;
}

// ---------------- y + node projections (fused), 8 nodes/block ----------------
__global__ __launch_bounds__(256) void k_y8(const float* __restrict__ xc,
                                            const float* __restrict__ Wl,
                                            const float* __restrict__ Wr,
                                            const float* __restrict__ Wsh,
                                            const float* __restrict__ Wwt,
                                            int layer,
                                            float* __restrict__ y,
                                            float* __restrict__ aR, float* __restrict__ aC,
                                            float* __restrict__ wR, float* __restrict__ wC) {
    __shared__ float wrs[32 * 33];
    __shared__ float wls[9];
    __shared__ float xcs[8][96];
    __shared__ float ws1[192], wt[192];
    int tid = threadIdx.x;
    for (int i = tid; i < 1024; i += 256) wrs[(i >> 5) * 33 + (i & 31)] = Wr[i];
    if (tid < 9) wls[tid] = Wl[tid];
    if (tid < 192) {
        ws1[tid] = Wsh[(layer * 3 + 1) * 192 + tid];  // only row 1 of W_sheaf survives Cayley (D=2)
        wt[tid]  = Wwt[layer * 192 + tid];
    }
    int n0 = blockIdx.x * 8;
    for (int i = tid; i < 768; i += 256) {
        int n = n0 + i / 96;
        xcs[i / 96][i % 96] = (n < NN) ? xc[n * 96 + i % 96] : 0.0f;
    }
    __syncthreads();
    int node = tid >> 5, c = tid & 31;
    int n = n0 + node;
    // --- sheaf/weight projections: reduce over 96 with 32 lanes (3 k's each) ---
    float a1 = 0, a2 = 0, a3 = 0, a4 = 0;
#pragma unroll
    for (int j = 0; j < 3; ++j) {
        int k = j * 32 + c;
        float xv = xcs[node][k];
        a1 = fmaf(xv, ws1[k], a1);
        a2 = fmaf(xv, ws1[96 + k], a2);
        a3 = fmaf(xv, wt[k], a3);
        a4 = fmaf(xv, wt[96 + k], a4);
    }
#pragma unroll
    for (int off = 16; off; off >>= 1) {
        a1 += __shfl_xor(a1, off);
        a2 += __shfl_xor(a2, off);
        a3 += __shfl_xor(a3, off);
        a4 += __shfl_xor(a4, off);
    }
    if (c == 0 && n < NN) { aR[n] = a1; aC[n] = a2; wR[n] = a3; wC[n] = a4; }
    // --- y = Wl · (xc · Wr^T) ---
    if (n < NN) {
        float t0 = 0, t1 = 0, t2 = 0;
        const float* wr = &wrs[c * 33];
        const float* xr = xcs[node];
#pragma unroll
        for (int h = 0; h < 32; ++h) {
            float w = wr[h];
            t0 = fmaf(xr[h], w, t0);
            t1 = fmaf(xr[32 + h], w, t1);
            t2 = fmaf(xr[64 + h], w, t2);
        }
        y[n * 96 + c]      = wls[0] * t0 + wls[1] * t1 + wls[2] * t2;
        y[n * 96 + 32 + c] = wls[3] * t0 + wls[4] * t1 + wls[5] * t2;
        y[n * 96 + 64 + c] = wls[6] * t0 + wls[7] * t1 + wls[8] * t2;
    }
}

// ---------------- per-edge coefficients + degree ----------------
__global__ __launch_bounds__(256) void k_edge_coef(const int* __restrict__ row, const int* __restrict__ col,
                                                   const float* __restrict__ aR, const float* __restrict__ aC,
                                                   const float* __restrict__ wR, const float* __restrict__ wC,
                                                   float* __restrict__ Cc, float* __restrict__ Sc,
                                                   float* __restrict__ w2e, float* __restrict__ deg) {
    int e = blockIdx.x * 256 + threadIdx.x;
    if (e >= E2) return;
    int u = row[e], v = col[e];
    float a_e = tanhf(aR[u] + aC[v]);
    float a_r = tanhf(aR[v] + aC[u]);
    float wd_e = sigmoidf(wR[u] + wC[v]);
    float wd_r = sigmoidf(wR[v] + wC[u]);
    float w = wd_e * wd_r;
    float w2 = w * w;
    float ie = 1.0f / (1.0f + a_e * a_e), ir = 1.0f / (1.0f + a_r * a_r);
    float ce = (1.0f - a_e * a_e) * ie, se = 2.0f * a_e * ie;
    float cr = (1.0f - a_r * a_r) * ir, sr = 2.0f * a_r * ir;
    Cc[e] = ce * cr + se * sr;   // T = Q_e^T Q_rev
    Sc[e] = ce * sr - se * cr;
    w2e[e] = w2;
    atomicAdd(&deg[u], w2);
}

__global__ __launch_bounds__(256) void k_dinv(const float* __restrict__ deg, float* __restrict__ dinv) {
    int n = blockIdx.x * 256 + threadIdx.x;
    if (n >= NN) return;
    float d = deg[n];
    dinv[n] = d > 0.0f ? rsqrtf(fmaxf(d, 1e-30f)) : 0.0f;
}

// ---------------- gather + residual update (fused; no atomics, no agg buffer)
__global__ __launch_bounds__(256) void k_gather_update(const int* __restrict__ start, const int* __restrict__ cnt,
                                                       const int* __restrict__ csr, const int* __restrict__ col,
                                                       const float* __restrict__ Cc, const float* __restrict__ Sc,
                                                       const float* __restrict__ w2e,
                                                       const float* __restrict__ dinv, const float* __restrict__ deg,
                                                       const float* __restrict__ y, const float* __restrict__ eps,
                                                       int layer, float* __restrict__ xc) {
    int tid = threadIdx.x;
    int node = tid >> 5, c = tid & 31;
    int n = blockIdx.x * 8 + node;
    if (n >= NN) return;
    int s0 = start[n], e_cnt = cnt[n];
    float du = dinv[n];
    float acc0 = 0, acc1 = 0, acc2 = 0;
    for (int s = s0; s < s0 + e_cnt; ++s) {
        int eid = csr[s];
        int v = col[eid];
        float cn = w2e[eid] * du * dinv[v];
        float C = Cc[eid], S = Sc[eid];
        float y0 = y[v * 96 + c], y1 = y[v * 96 + 32 + c], y2 = y[v * 96 + 64 + c];
        acc0 = fmaf(cn, fmaf(C, y0, -S * y1), acc0);
        acc1 = fmaf(cn, fmaf(S, y0, C * y1), acc1);
        acc2 = fmaf(cn, y2, acc2);
    }
    float diag = deg[n] > 0.0f ? 1.0f : 0.0f;
    float c0 = 1.0f + tanhf(eps[layer * 3 + 0]);
    float c1 = 1.0f + tanhf(eps[layer * 3 + 1]);
    float c2 = 1.0f + tanhf(eps[layer * 3 + 2]);
    int base = n * 96 + c;
    float z0 = eluf(diag * y[base]      - acc0);
    float z1 = eluf(diag * y[base + 32] - acc1);
    float z2 = eluf(diag * y[base + 64] - acc2);
    xc[base]      = c0 * xc[base]      - z0;
    xc[base + 32] = c1 * xc[base + 32] - z1;
    xc[base + 64] = c2 * xc[base + 64] - z2;
}

// ---------------- lin2: out = xc @ W2^T + b2 -> f32 [NN,32]
__global__ __launch_bounds__(256) void k_lin2(const float* __restrict__ xc, const float* __restrict__ W2,
                                              const float* __restrict__ bias2, float* __restrict__ out) {
    __shared__ float w2s[32 * 97];
    __shared__ float xcs[8][96];
    int tid = threadIdx.x;
    for (int i = tid; i < 32 * 96; i += 256) w2s[(i / 96) * 97 + (i % 96)] = W2[i];
    int n0 = blockIdx.x * 8;
    for (int i = tid; i < 8 * 96; i += 256) {
        int n = n0 + i / 96;
        if (n < NN) xcs[i / 96][i % 96] = xc[n * 96 + i % 96];
    }
    __syncthreads();
    int ln = tid >> 5, c = tid & 31;
    int n = n0 + ln;
    if (n >= NN) return;
    float acc = bias2[c];
    const float* xr = xcs[ln];
    const float* wr = &w2s[c * 97];
#pragma unroll 8
    for (int k = 0; k < 96; ++k) acc = fmaf(xr[k], wr[k], acc);
    out[n * 32 + c] = acc;
}

extern "C" void kernel_launch(void* const* d_in, const int* in_sizes, int n_in,
                              void* d_out, int out_size, void* d_ws, size_t ws_size,
                              hipStream_t stream) {
    const float* x     = (const float*)d_in[0];
    const int*   ei    = (const int*)d_in[1];
    const float* W1    = (const float*)d_in[2];
    const float* b1    = (const float*)d_in[3];
    const float* W2    = (const float*)d_in[4];
    const float* bias2 = (const float*)d_in[5];
    const float* Wl_in = (const float*)d_in[6];
    const float* Wr_in = (const float*)d_in[7];
    const float* eps   = (const float*)d_in[8];
    const float* Wsh   = (const float*)d_in[9];
    const float* Wwt   = (const float*)d_in[10];
    float* out = (float*)d_out;
    const int* row = ei;        // edge_index[0]
    const int* col = ei + E2;   // edge_index[1]

    float* p    = (float*)d_ws;
    float* xc   = p; p += NN * 96;
    float* y    = p; p += NN * 96;
    float* Cc   = p; p += E2;
    float* Sc   = p; p += E2;
    float* w2e  = p; p += E2;
    float* aR   = p; p += NN;
    float* aC   = p; p += NN;
    float* wRp  = p; p += NN;
    float* wCp  = p; p += NN;
    float* deg  = p; p += NN;
    float* dinv = p; p += NN;
    float* Wl_n = p; p += 32;
    float* Wr_n = p; p += 2048;
    int* cnt   = (int*)p; p += NN;
    int* start = (int*)p; p += NN;
    int* fill  = (int*)p; p += NN;
    int* csr   = (int*)p; p += E2;
    int* bsum  = (int*)p; p += 256;
    int* bofs  = (int*)p; p += 256;

    const int NB = (NN + 255) / 256;   // 196
    const int EB = (E2 + 255) / 256;   // 1563

    k_lin1<<<(NN + 7) / 8, 256, 0, stream>>>(x, W1, b1, xc);
    k_spectral<<<2, 64, 0, stream>>>(Wl_in, Wr_in, Wl_n, Wr_n);

    // CSR build (once per call)
    hipMemsetAsync(cnt, 0, NN * sizeof(int), stream);
    hipMemsetAsync(fill, 0, NN * sizeof(int), stream);
    k_hist<<<EB, 256, 0, stream>>>(row, cnt);
    k_scan1<<<NB, 256, 0, stream>>>(cnt, start, bsum);
    k_scan2<<<1, 256, 0, stream>>>(bsum, bofs, NB);
    k_scan3<<<NB, 256, 0, stream>>>(start, bofs);
    k_fill<<<EB, 256, 0, stream>>>(row, start, fill, csr);

    for (int l = 0; l < 2; ++l) {
        k_y8<<<(NN + 7) / 8, 256, 0, stream>>>(xc, Wl_n + l * 9, Wr_n + l * 1024, Wsh, Wwt, l,
                                               y, aR, aC, wRp, wCp);
        hipMemsetAsync(deg, 0, NN * sizeof(float), stream);
        k_edge_coef<<<EB, 256, 0, stream>>>(row, col, aR, aC, wRp, wCp, Cc, Sc, w2e, deg);
        k_dinv<<<NB, 256, 0, stream>>>(deg, dinv);
        k_gather_update<<<(NN + 7) / 8, 256, 0, stream>>>(start, cnt, csr, col, Cc, Sc, w2e,
                                                          dinv, deg, y, eps, l, xc);
    }
    k_lin2<<<(NN + 7) / 8, 256, 0, stream>>>(xc, W2, bias2, out);
}

// Round 4
// 435.738 us; speedup vs baseline: 1.5195x; 1.1461x over previous
//
#include <hip/hip_runtime.h>
#include <hip/hip_bf16.h>

#define NN   50000
#define E2   400000

typedef __attribute__((ext_vector_type(8))) short short8;
typedef __attribute__((ext_vector_type(4))) float f32x4;

__device__ __forceinline__ float eluf(float x) { return x > 0.0f ? x : expm1f(x); }
__device__ __forceinline__ float sigmoidf(float x) { return 1.0f / (1.0f + expf(-x)); }
__device__ __forceinline__ unsigned rne_bf16(float x) {
    unsigned u = __float_as_uint(x);
    return (u + 0x7fffu + ((u >> 16) & 1u)) >> 16;
}

// ---------------- split a f32 weight matrix into hi/lo bf16 (one-time setup)
__global__ __launch_bounds__(256) void k_splitw(const float* __restrict__ W, int n,
                                                unsigned short* __restrict__ hi,
                                                unsigned short* __restrict__ lo) {
    int i = blockIdx.x * 256 + threadIdx.x;
    if (i >= n) return;
    float x = W[i];
    unsigned h = rne_bf16(x);
    hi[i] = (unsigned short)h;
    lo[i] = (unsigned short)rne_bf16(x - __uint_as_float(h << 16));
}

// ---------------- MFMA GEMM: out[M,N] = act(X[M,K] @ W[N,K]^T + b), split-bf16 (3 products)
// Block: 256 thr = 4 waves, 64 rows/block, full N. W staged hi/lo in LDS (padded).
template<int K, int N, bool ELU>
__global__ __launch_bounds__(256) void k_gemm_mfma(const float* __restrict__ X,
                                                   const unsigned short* __restrict__ Whi,
                                                   const unsigned short* __restrict__ Wlo,
                                                   const float* __restrict__ bias,
                                                   float* __restrict__ out) {
    constexpr int KP = K + 8;          // pad: row stride in shorts (mult of 8, 2-way bank alias only)
    constexpr int NT = N / 16;
    constexpr int KS = K / 32;
    __shared__ __align__(16) unsigned short whi[N * KP];
    __shared__ __align__(16) unsigned short wlo[N * KP];
    int tid = threadIdx.x;
    for (int i = tid; i < N * K / 2; i += 256) {   // 2 shorts per iter via uint
        unsigned vh = ((const unsigned*)Whi)[i];
        unsigned vl = ((const unsigned*)Wlo)[i];
        int e = i * 2, r = e / K, c = e % K;
        *(unsigned*)&whi[r * KP + c] = vh;
        *(unsigned*)&wlo[r * KP + c] = vl;
    }
    __syncthreads();
    int wave = tid >> 6, lane = tid & 63;
    int quad = lane >> 4, r16 = lane & 15;
    long m = (long)blockIdx.x * 64 + wave * 16 + r16;
    long mc = m < NN ? m : (NN - 1);               // clamp OOB A-loads (stores guarded)
    const float* xrow = X + mc * K + quad * 8;
    f32x4 acc[NT];
#pragma unroll
    for (int t = 0; t < NT; ++t) acc[t] = (f32x4){0.f, 0.f, 0.f, 0.f};
#pragma unroll
    for (int ks = 0; ks < KS; ++ks) {
        const float4* xp = (const float4*)(xrow + ks * 32);
        float4 p0 = xp[0], p1 = xp[1];
        float xv[8] = {p0.x, p0.y, p0.z, p0.w, p1.x, p1.y, p1.z, p1.w};
        short8 a_hi, a_lo;
#pragma unroll
        for (int j = 0; j < 8; ++j) {
            unsigned h = rne_bf16(xv[j]);
            a_hi[j] = (short)h;
            a_lo[j] = (short)rne_bf16(xv[j] - __uint_as_float(h << 16));
        }
#pragma unroll
        for (int t = 0; t < NT; ++t) {
            int ro = (t * 16 + r16) * KP + ks * 32 + quad * 8;
            short8 bh = *(const short8*)&whi[ro];
            short8 bl = *(const short8*)&wlo[ro];
            acc[t] = __builtin_amdgcn_mfma_f32_16x16x32_bf16(a_hi, bh, acc[t], 0, 0, 0);
            acc[t] = __builtin_amdgcn_mfma_f32_16x16x32_bf16(a_lo, bh, acc[t], 0, 0, 0);
            acc[t] = __builtin_amdgcn_mfma_f32_16x16x32_bf16(a_hi, bl, acc[t], 0, 0, 0);
        }
    }
    // C/D layout: col = lane&15, row = quad*4 + reg  [m89-verified]
    long mbase = (long)blockIdx.x * 64 + wave * 16 + quad * 4;
#pragma unroll
    for (int t = 0; t < NT; ++t) {
        float b = bias[t * 16 + r16];
#pragma unroll
        for (int rr = 0; rr < 4; ++rr) {
            long mm = mbase + rr;
            if (mm < NN) {
                float v = acc[t][rr] + b;
                if (ELU) v = eluf(v);
                out[mm * N + t * 16 + r16] = v;
            }
        }
    }
}

// ---------------- spectral norm of W_left[l] (3x3) and W_right[l] (32x32)
__global__ __launch_bounds__(64) void k_spectral(const float* __restrict__ Wl_in,
                                                 const float* __restrict__ Wr_in,
                                                 float* __restrict__ Wl_out,
                                                 float* __restrict__ Wr_out) {
    int l = blockIdx.x, t = threadIdx.x;
    __shared__ float W[32 * 33];
    __shared__ float us[32], vs[32], tmp[32];
    __shared__ float scal;
    for (int i = t; i < 1024; i += 64) W[(i >> 5) * 33 + (i & 31)] = Wr_in[l * 1024 + i];
    if (t < 32) us[t] = 0.17677669529663688f;
    __syncthreads();
    for (int it = 0; it < 20; ++it) {
        if (t < 32) { float a = 0; for (int r = 0; r < 32; ++r) a = fmaf(W[r * 33 + t], us[r], a); tmp[t] = a; }
        __syncthreads();
        if (t == 0) { float s = 0; for (int c = 0; c < 32; ++c) s += tmp[c] * tmp[c]; scal = 1.0f / (sqrtf(s) + 1e-12f); }
        __syncthreads();
        if (t < 32) vs[t] = tmp[t] * scal;
        __syncthreads();
        if (t < 32) { float a = 0; for (int c = 0; c < 32; ++c) a = fmaf(W[t * 33 + c], vs[c], a); tmp[t] = a; }
        __syncthreads();
        if (t == 0) { float s = 0; for (int r = 0; r < 32; ++r) s += tmp[r] * tmp[r]; scal = 1.0f / (sqrtf(s) + 1e-12f); }
        __syncthreads();
        if (t < 32) us[t] = tmp[t] * scal;
        __syncthreads();
    }
    if (t < 32) { float a = 0; for (int r = 0; r < 32; ++r) a = fmaf(W[r * 33 + t], us[r], a); tmp[t] = a; }
    __syncthreads();
    if (t == 0) {
        float s = 0; for (int c = 0; c < 32; ++c) s += tmp[c] * tmp[c];
        scal = (sqrtf(s) + 1e-12f) / s;  // 1/sigma
    }
    __syncthreads();
    for (int i = t; i < 1024; i += 64) Wr_out[l * 1024 + i] = W[(i >> 5) * 33 + (i & 31)] * scal;

    if (t == 0) {
        float M[9];
        for (int i = 0; i < 9; ++i) M[i] = Wl_in[l * 9 + i];
        float u[3] = {0.5773502691896258f, 0.5773502691896258f, 0.5773502691896258f};
        float v[3], u2[3];
        for (int it = 0; it < 20; ++it) {
            float s = 0;
            for (int c = 0; c < 3; ++c) { v[c] = M[c] * u[0] + M[3 + c] * u[1] + M[6 + c] * u[2]; s += v[c] * v[c]; }
            float inv = 1.0f / (sqrtf(s) + 1e-12f);
            for (int c = 0; c < 3; ++c) v[c] *= inv;
            s = 0;
            for (int r = 0; r < 3; ++r) { u2[r] = M[r * 3] * v[0] + M[r * 3 + 1] * v[1] + M[r * 3 + 2] * v[2]; s += u2[r] * u2[r]; }
            inv = 1.0f / (sqrtf(s) + 1e-12f);
            for (int r = 0; r < 3; ++r) u[r] = u2[r] * inv;
        }
        float s = 0;
        for (int c = 0; c < 3; ++c) { v[c] = M[c] * u[0] + M[3 + c] * u[1] + M[6 + c] * u[2]; s += v[c] * v[c]; }
        float inv = (sqrtf(s) + 1e-12f) / s;
        for (int i = 0; i < 9; ++i) Wl_out[l * 9 + i] = M[i] * inv;
    }
}

// ---------------- CSR build --------------------------------------------------
__global__ __launch_bounds__(256) void k_hist(const int* __restrict__ row, int* __restrict__ cnt) {
    int e = blockIdx.x * 256 + threadIdx.x;
    if (e < E2) atomicAdd(&cnt[row[e]], 1);
}
__global__ __launch_bounds__(256) void k_scan1(const int* __restrict__ cnt, int* __restrict__ start,
                                               int* __restrict__ bsum) {
    __shared__ int s[256];
    int b = blockIdx.x, t = threadIdx.x;
    int i = b * 256 + t;
    int v = (i < NN) ? cnt[i] : 0;
    s[t] = v;
    __syncthreads();
    for (int off = 1; off < 256; off <<= 1) {
        int add = (t >= off) ? s[t - off] : 0;
        __syncthreads();
        s[t] += add;
        __syncthreads();
    }
    if (i < NN) start[i] = s[t] - v;
    if (t == 255) bsum[b] = s[t];
}
__global__ __launch_bounds__(256) void k_scan2(const int* __restrict__ bsum, int* __restrict__ bofs,
                                               int nb) {
    __shared__ int s[256];
    int t = threadIdx.x;
    int v = (t < nb) ? bsum[t] : 0;
    s[t] = v;
    __syncthreads();
    for (int off = 1; off < 256; off <<= 1) {
        int add = (t >= off) ? s[t - off] : 0;
        __syncthreads();
        s[t] += add;
        __syncthreads();
    }
    if (t < nb) bofs[t] = s[t] - v;
}
__global__ __launch_bounds__(256) void k_scan3(int* __restrict__ start, const int* __restrict__ bofs) {
    int i = blockIdx.x * 256 + threadIdx.x;
    if (i < NN) start[i] += bofs[i >> 8];
}
__global__ __launch_bounds__(256) void k_fill(const int* __restrict__ row, const int* __restrict__ start,
                                              int* __restrict__ fill, int* __restrict__ csr) {
    int e = blockIdx.x * 256 + threadIdx.x;
    if (e >= E2) return;
    int u = row[e];
    int slot = start[u] + atomicAdd(&fill[u], 1);
    csr[slot] = e;
}

// ---------------- y + node projections (fused), 8 nodes/block ----------------
__global__ __launch_bounds__(256) void k_y8(const float* __restrict__ xc,
                                            const float* __restrict__ Wl,
                                            const float* __restrict__ Wr,
                                            const float* __restrict__ Wsh,
                                            const float* __restrict__ Wwt,
                                            int layer,
                                            float* __restrict__ y,
                                            float* __restrict__ aR, float* __restrict__ aC,
                                            float* __restrict__ wR, float* __restrict__ wC) {
    __shared__ float wrs[32 * 33];
    __shared__ float wls[9];
    __shared__ float xcs[8][96];
    __shared__ float ws1[192], wt[192];
    int tid = threadIdx.x;
    for (int i = tid; i < 1024; i += 256) wrs[(i >> 5) * 33 + (i & 31)] = Wr[i];
    if (tid < 9) wls[tid] = Wl[tid];
    if (tid < 192) {
        ws1[tid] = Wsh[(layer * 3 + 1) * 192 + tid];  // only row 1 of W_sheaf survives Cayley (D=2)
        wt[tid]  = Wwt[layer * 192 + tid];
    }
    int n0 = blockIdx.x * 8;
    for (int i = tid; i < 768; i += 256) {
        int n = n0 + i / 96;
        xcs[i / 96][i % 96] = (n < NN) ? xc[n * 96 + i % 96] : 0.0f;
    }
    __syncthreads();
    int node = tid >> 5, c = tid & 31;
    int n = n0 + node;
    float a1 = 0, a2 = 0, a3 = 0, a4 = 0;
#pragma unroll
    for (int j = 0; j < 3; ++j) {
        int k = j * 32 + c;
        float xv = xcs[node][k];
        a1 = fmaf(xv, ws1[k], a1);
        a2 = fmaf(xv, ws1[96 + k], a2);
        a3 = fmaf(xv, wt[k], a3);
        a4 = fmaf(xv, wt[96 + k], a4);
    }
#pragma unroll
    for (int off = 16; off; off >>= 1) {
        a1 += __shfl_xor(a1, off);
        a2 += __shfl_xor(a2, off);
        a3 += __shfl_xor(a3, off);
        a4 += __shfl_xor(a4, off);
    }
    if (c == 0 && n < NN) { aR[n] = a1; aC[n] = a2; wR[n] = a3; wC[n] = a4; }
    if (n < NN) {
        float t0 = 0, t1 = 0, t2 = 0;
        const float* wr = &wrs[c * 33];
        const float* xr = xcs[node];
#pragma unroll
        for (int h = 0; h < 32; ++h) {
            float w = wr[h];
            t0 = fmaf(xr[h], w, t0);
            t1 = fmaf(xr[32 + h], w, t1);
            t2 = fmaf(xr[64 + h], w, t2);
        }
        y[n * 96 + c]      = wls[0] * t0 + wls[1] * t1 + wls[2] * t2;
        y[n * 96 + 32 + c] = wls[3] * t0 + wls[4] * t1 + wls[5] * t2;
        y[n * 96 + 64 + c] = wls[6] * t0 + wls[7] * t1 + wls[8] * t2;
    }
}

// ---------------- per-edge coefficients + degree ----------------
__global__ __launch_bounds__(256) void k_edge_coef(const int* __restrict__ row, const int* __restrict__ col,
                                                   const float* __restrict__ aR, const float* __restrict__ aC,
                                                   const float* __restrict__ wR, const float* __restrict__ wC,
                                                   float* __restrict__ Cc, float* __restrict__ Sc,
                                                   float* __restrict__ w2e, float* __restrict__ deg) {
    int e = blockIdx.x * 256 + threadIdx.x;
    if (e >= E2) return;
    int u = row[e], v = col[e];
    float a_e = tanhf(aR[u] + aC[v]);
    float a_r = tanhf(aR[v] + aC[u]);
    float wd_e = sigmoidf(wR[u] + wC[v]);
    float wd_r = sigmoidf(wR[v] + wC[u]);
    float w = wd_e * wd_r;
    float w2 = w * w;
    float ie = 1.0f / (1.0f + a_e * a_e), ir = 1.0f / (1.0f + a_r * a_r);
    float ce = (1.0f - a_e * a_e) * ie, se = 2.0f * a_e * ie;
    float cr = (1.0f - a_r * a_r) * ir, sr = 2.0f * a_r * ir;
    Cc[e] = ce * cr + se * sr;   // T = Q_e^T Q_rev
    Sc[e] = ce * sr - se * cr;
    w2e[e] = w2;
    atomicAdd(&deg[u], w2);
}

__global__ __launch_bounds__(256) void k_dinv(const float* __restrict__ deg, float* __restrict__ dinv) {
    int n = blockIdx.x * 256 + threadIdx.x;
    if (n >= NN) return;
    float d = deg[n];
    dinv[n] = d > 0.0f ? rsqrtf(fmaxf(d, 1e-30f)) : 0.0f;
}

// ---------------- gather + residual update (fused; no atomics, no agg buffer)
__global__ __launch_bounds__(256) void k_gather_update(const int* __restrict__ start, const int* __restrict__ cnt,
                                                       const int* __restrict__ csr, const int* __restrict__ col,
                                                       const float* __restrict__ Cc, const float* __restrict__ Sc,
                                                       const float* __restrict__ w2e,
                                                       const float* __restrict__ dinv, const float* __restrict__ deg,
                                                       const float* __restrict__ y, const float* __restrict__ eps,
                                                       int layer, float* __restrict__ xc) {
    int tid = threadIdx.x;
    int node = tid >> 5, c = tid & 31;
    int n = blockIdx.x * 8 + node;
    if (n >= NN) return;
    int s0 = start[n], e_cnt = cnt[n];
    float du = dinv[n];
    float acc0 = 0, acc1 = 0, acc2 = 0;
    for (int s = s0; s < s0 + e_cnt; ++s) {
        int eid = csr[s];
        int v = col[eid];
        float cn = w2e[eid] * du * dinv[v];
        float C = Cc[eid], S = Sc[eid];
        float y0 = y[v * 96 + c], y1 = y[v * 96 + 32 + c], y2 = y[v * 96 + 64 + c];
        acc0 = fmaf(cn, fmaf(C, y0, -S * y1), acc0);
        acc1 = fmaf(cn, fmaf(S, y0, C * y1), acc1);
        acc2 = fmaf(cn, y2, acc2);
    }
    float diag = deg[n] > 0.0f ? 1.0f : 0.0f;
    float c0 = 1.0f + tanhf(eps[layer * 3 + 0]);
    float c1 = 1.0f + tanhf(eps[layer * 3 + 1]);
    float c2 = 1.0f + tanhf(eps[layer * 3 + 2]);
    int base = n * 96 + c;
    float z0 = eluf(diag * y[base]      - acc0);
    float z1 = eluf(diag * y[base + 32] - acc1);
    float z2 = eluf(diag * y[base + 64] - acc2);
    xc[base]      = c0 * xc[base]      - z0;
    xc[base + 32] = c1 * xc[base + 32] - z1;
    xc[base + 64] = c2 * xc[base + 64] - z2;
}

extern "C" void kernel_launch(void* const* d_in, const int* in_sizes, int n_in,
                              void* d_out, int out_size, void* d_ws, size_t ws_size,
                              hipStream_t stream) {
    const float* x     = (const float*)d_in[0];
    const int*   ei    = (const int*)d_in[1];
    const float* W1    = (const float*)d_in[2];
    const float* b1    = (const float*)d_in[3];
    const float* W2    = (const float*)d_in[4];
    const float* bias2 = (const float*)d_in[5];
    const float* Wl_in = (const float*)d_in[6];
    const float* Wr_in = (const float*)d_in[7];
    const float* eps   = (const float*)d_in[8];
    const float* Wsh   = (const float*)d_in[9];
    const float* Wwt   = (const float*)d_in[10];
    float* out = (float*)d_out;
    const int* row = ei;        // edge_index[0]
    const int* col = ei + E2;   // edge_index[1]

    float* p    = (float*)d_ws;
    float* xc   = p; p += NN * 96;
    float* y    = p; p += NN * 96;
    float* Cc   = p; p += E2;
    float* Sc   = p; p += E2;
    float* w2e  = p; p += E2;
    float* aR   = p; p += NN;
    float* aC   = p; p += NN;
    float* wRp  = p; p += NN;
    float* wCp  = p; p += NN;
    float* deg  = p; p += NN;
    float* dinv = p; p += NN;
    float* Wl_n = p; p += 32;
    float* Wr_n = p; p += 2048;
    int* cnt   = (int*)p; p += NN;
    int* start = (int*)p; p += NN;
    int* fill  = (int*)p; p += NN;
    int* csr   = (int*)p; p += E2;
    int* bsum  = (int*)p; p += 256;
    int* bofs  = (int*)p; p += 256;
    unsigned short* w1hi = (unsigned short*)p; p += 96 * 128 / 2;
    unsigned short* w1lo = (unsigned short*)p; p += 96 * 128 / 2;
    unsigned short* w2hi = (unsigned short*)p; p += 32 * 96 / 2;
    unsigned short* w2lo = (unsigned short*)p; p += 32 * 96 / 2;

    const int NB = (NN + 255) / 256;
    const int EB = (E2 + 255) / 256;
    const int MB = (NN + 63) / 64;     // 782 row-blocks for MFMA GEMMs

    k_splitw<<<(96 * 128 + 255) / 256, 256, 0, stream>>>(W1, 96 * 128, w1hi, w1lo);
    k_splitw<<<(32 * 96 + 255) / 256, 256, 0, stream>>>(W2, 32 * 96, w2hi, w2lo);
    k_gemm_mfma<128, 96, true><<<MB, 256, 0, stream>>>(x, w1hi, w1lo, b1, xc);
    k_spectral<<<2, 64, 0, stream>>>(Wl_in, Wr_in, Wl_n, Wr_n);

    // CSR build (once per call)
    hipMemsetAsync(cnt, 0, NN * sizeof(int), stream);
    hipMemsetAsync(fill, 0, NN * sizeof(int), stream);
    k_hist<<<EB, 256, 0, stream>>>(row, cnt);
    k_scan1<<<NB, 256, 0, stream>>>(cnt, start, bsum);
    k_scan2<<<1, 256, 0, stream>>>(bsum, bofs, NB);
    k_scan3<<<NB, 256, 0, stream>>>(start, bofs);
    k_fill<<<EB, 256, 0, stream>>>(row, start, fill, csr);

    for (int l = 0; l < 2; ++l) {
        k_y8<<<(NN + 7) / 8, 256, 0, stream>>>(xc, Wl_n + l * 9, Wr_n + l * 1024, Wsh, Wwt, l,
                                               y, aR, aC, wRp, wCp);
        hipMemsetAsync(deg, 0, NN * sizeof(float), stream);
        k_edge_coef<<<EB, 256, 0, stream>>>(row, col, aR, aC, wRp, wCp, Cc, Sc, w2e, deg);
        k_dinv<<<NB, 256, 0, stream>>>(deg, dinv);
        k_gather_update<<<(NN + 7) / 8, 256, 0, stream>>>(start, cnt, csr, col, Cc, Sc, w2e,
                                                          dinv, deg, y, eps, l, xc);
    }
    k_gemm_mfma<96, 32, false><<<MB, 256, 0, stream>>>(xc, w2hi, w2lo, bias2, out);
}

// Round 5
// 377.554 us; speedup vs baseline: 1.7536x; 1.1541x over previous
//
#include <hip/hip_runtime.h>
#include <hip/hip_bf16.h>

#define NN   50000
#define E0   200000
#define E2   400000

typedef __attribute__((ext_vector_type(8))) short short8;
typedef __attribute__((ext_vector_type(4))) float f32x4;

__device__ __forceinline__ float eluf(float x) { return x > 0.0f ? x : expm1f(x); }
__device__ __forceinline__ float sigmoidf(float x) { return 1.0f / (1.0f + expf(-x)); }
__device__ __forceinline__ unsigned rne_bf16(float x) {
    unsigned u = __float_as_uint(x);
    return (u + 0x7fffu + ((u >> 16) & 1u)) >> 16;
}

// ---------------- split a f32 weight matrix into hi/lo bf16 (one-time setup)
__global__ __launch_bounds__(256) void k_splitw(const float* __restrict__ W, int n,
                                                unsigned short* __restrict__ hi,
                                                unsigned short* __restrict__ lo) {
    int i = blockIdx.x * 256 + threadIdx.x;
    if (i >= n) return;
    float x = W[i];
    unsigned h = rne_bf16(x);
    hi[i] = (unsigned short)h;
    lo[i] = (unsigned short)rne_bf16(x - __uint_as_float(h << 16));
}

// ---------------- MFMA GEMM: out[M,N] = act(X[M,K] @ W[N,K]^T + b), split-bf16 (3 products)
template<int K, int N, bool ELU>
__global__ __launch_bounds__(256) void k_gemm_mfma(const float* __restrict__ X,
                                                   const unsigned short* __restrict__ Whi,
                                                   const unsigned short* __restrict__ Wlo,
                                                   const float* __restrict__ bias,
                                                   float* __restrict__ out) {
    constexpr int KP = K + 8;
    constexpr int NT = N / 16;
    constexpr int KS = K / 32;
    __shared__ __align__(16) unsigned short whi[N * KP];
    __shared__ __align__(16) unsigned short wlo[N * KP];
    int tid = threadIdx.x;
    for (int i = tid; i < N * K / 2; i += 256) {
        unsigned vh = ((const unsigned*)Whi)[i];
        unsigned vl = ((const unsigned*)Wlo)[i];
        int e = i * 2, r = e / K, c = e % K;
        *(unsigned*)&whi[r * KP + c] = vh;
        *(unsigned*)&wlo[r * KP + c] = vl;
    }
    __syncthreads();
    int wave = tid >> 6, lane = tid & 63;
    int quad = lane >> 4, r16 = lane & 15;
    long m = (long)blockIdx.x * 64 + wave * 16 + r16;
    long mc = m < NN ? m : (NN - 1);
    const float* xrow = X + mc * K + quad * 8;
    f32x4 acc[NT];
#pragma unroll
    for (int t = 0; t < NT; ++t) acc[t] = (f32x4){0.f, 0.f, 0.f, 0.f};
#pragma unroll
    for (int ks = 0; ks < KS; ++ks) {
        const float4* xp = (const float4*)(xrow + ks * 32);
        float4 p0 = xp[0], p1 = xp[1];
        float xv[8] = {p0.x, p0.y, p0.z, p0.w, p1.x, p1.y, p1.z, p1.w};
        short8 a_hi, a_lo;
#pragma unroll
        for (int j = 0; j < 8; ++j) {
            unsigned h = rne_bf16(xv[j]);
            a_hi[j] = (short)h;
            a_lo[j] = (short)rne_bf16(xv[j] - __uint_as_float(h << 16));
        }
#pragma unroll
        for (int t = 0; t < NT; ++t) {
            int ro = (t * 16 + r16) * KP + ks * 32 + quad * 8;
            short8 bh = *(const short8*)&whi[ro];
            short8 bl = *(const short8*)&wlo[ro];
            acc[t] = __builtin_amdgcn_mfma_f32_16x16x32_bf16(a_hi, bh, acc[t], 0, 0, 0);
            acc[t] = __builtin_amdgcn_mfma_f32_16x16x32_bf16(a_lo, bh, acc[t], 0, 0, 0);
            acc[t] = __builtin_amdgcn_mfma_f32_16x16x32_bf16(a_hi, bl, acc[t], 0, 0, 0);
        }
    }
    long mbase = (long)blockIdx.x * 64 + wave * 16 + quad * 4;
#pragma unroll
    for (int t = 0; t < NT; ++t) {
        float b = bias[t * 16 + r16];
#pragma unroll
        for (int rr = 0; rr < 4; ++rr) {
            long mm = mbase + rr;
            if (mm < NN) {
                float v = acc[t][rr] + b;
                if (ELU) v = eluf(v);
                out[mm * N + t * 16 + r16] = v;
            }
        }
    }
}

// ---------------- spectral norm of W_left[l] (3x3) and W_right[l] (32x32)
__global__ __launch_bounds__(64) void k_spectral(const float* __restrict__ Wl_in,
                                                 const float* __restrict__ Wr_in,
                                                 float* __restrict__ Wl_out,
                                                 float* __restrict__ Wr_out) {
    int l = blockIdx.x, t = threadIdx.x;
    __shared__ float W[32 * 33];
    __shared__ float us[32], vs[32], tmp[32];
    __shared__ float scal;
    for (int i = t; i < 1024; i += 64) W[(i >> 5) * 33 + (i & 31)] = Wr_in[l * 1024 + i];
    if (t < 32) us[t] = 0.17677669529663688f;
    __syncthreads();
    for (int it = 0; it < 20; ++it) {
        if (t < 32) { float a = 0; for (int r = 0; r < 32; ++r) a = fmaf(W[r * 33 + t], us[r], a); tmp[t] = a; }
        __syncthreads();
        if (t == 0) { float s = 0; for (int c = 0; c < 32; ++c) s += tmp[c] * tmp[c]; scal = 1.0f / (sqrtf(s) + 1e-12f); }
        __syncthreads();
        if (t < 32) vs[t] = tmp[t] * scal;
        __syncthreads();
        if (t < 32) { float a = 0; for (int c = 0; c < 32; ++c) a = fmaf(W[t * 33 + c], vs[c], a); tmp[t] = a; }
        __syncthreads();
        if (t == 0) { float s = 0; for (int r = 0; r < 32; ++r) s += tmp[r] * tmp[r]; scal = 1.0f / (sqrtf(s) + 1e-12f); }
        __syncthreads();
        if (t < 32) us[t] = tmp[t] * scal;
        __syncthreads();
    }
    if (t < 32) { float a = 0; for (int r = 0; r < 32; ++r) a = fmaf(W[r * 33 + t], us[r], a); tmp[t] = a; }
    __syncthreads();
    if (t == 0) {
        float s = 0; for (int c = 0; c < 32; ++c) s += tmp[c] * tmp[c];
        scal = (sqrtf(s) + 1e-12f) / s;  // 1/sigma
    }
    __syncthreads();
    for (int i = t; i < 1024; i += 64) Wr_out[l * 1024 + i] = W[(i >> 5) * 33 + (i & 31)] * scal;

    if (t == 0) {
        float M[9];
        for (int i = 0; i < 9; ++i) M[i] = Wl_in[l * 9 + i];
        float u[3] = {0.5773502691896258f, 0.5773502691896258f, 0.5773502691896258f};
        float v[3], u2[3];
        for (int it = 0; it < 20; ++it) {
            float s = 0;
            for (int c = 0; c < 3; ++c) { v[c] = M[c] * u[0] + M[3 + c] * u[1] + M[6 + c] * u[2]; s += v[c] * v[c]; }
            float inv = 1.0f / (sqrtf(s) + 1e-12f);
            for (int c = 0; c < 3; ++c) v[c] *= inv;
            s = 0;
            for (int r = 0; r < 3; ++r) { u2[r] = M[r * 3] * v[0] + M[r * 3 + 1] * v[1] + M[r * 3 + 2] * v[2]; s += u2[r] * u2[r]; }
            inv = 1.0f / (sqrtf(s) + 1e-12f);
            for (int r = 0; r < 3; ++r) u[r] = u2[r] * inv;
        }
        float s = 0;
        for (int c = 0; c < 3; ++c) { v[c] = M[c] * u[0] + M[3 + c] * u[1] + M[6 + c] * u[2]; s += v[c] * v[c]; }
        float inv = (sqrtf(s) + 1e-12f) / s;
        for (int i = 0; i < 9; ++i) Wl_out[l * 9 + i] = M[i] * inv;
    }
}

// ---------------- CSR build --------------------------------------------------
__global__ __launch_bounds__(256) void k_hist(const int* __restrict__ row, int* __restrict__ cnt) {
    int e = blockIdx.x * 256 + threadIdx.x;
    if (e < E2) atomicAdd(&cnt[row[e]], 1);
}
__global__ __launch_bounds__(256) void k_scan1(const int* __restrict__ cnt, int* __restrict__ start,
                                               int* __restrict__ bsum) {
    __shared__ int s[256];
    int b = blockIdx.x, t = threadIdx.x;
    int i = b * 256 + t;
    int v = (i < NN) ? cnt[i] : 0;
    s[t] = v;
    __syncthreads();
    for (int off = 1; off < 256; off <<= 1) {
        int add = (t >= off) ? s[t - off] : 0;
        __syncthreads();
        s[t] += add;
        __syncthreads();
    }
    if (i < NN) start[i] = s[t] - v;
    if (t == 255) bsum[b] = s[t];
}
__global__ __launch_bounds__(256) void k_scan2(const int* __restrict__ bsum, int* __restrict__ bofs,
                                               int nb) {
    __shared__ int s[256];
    int t = threadIdx.x;
    int v = (t < nb) ? bsum[t] : 0;
    s[t] = v;
    __syncthreads();
    for (int off = 1; off < 256; off <<= 1) {
        int add = (t >= off) ? s[t - off] : 0;
        __syncthreads();
        s[t] += add;
        __syncthreads();
    }
    if (t < nb) bofs[t] = s[t] - v;
}
__global__ __launch_bounds__(256) void k_scan3(int* __restrict__ start, const int* __restrict__ bofs) {
    int i = blockIdx.x * 256 + threadIdx.x;
    if (i < NN) start[i] += bofs[i >> 8];
}
__global__ __launch_bounds__(256) void k_fill(const int* __restrict__ row, const int* __restrict__ start,
                                              int* __restrict__ fill, int* __restrict__ eslot) {
    int e = blockIdx.x * 256 + threadIdx.x;
    if (e >= E2) return;
    int u = row[e];
    eslot[e] = start[u] + atomicAdd(&fill[u], 1);   // inverse CSR permutation
}

// ---------------- y + node projections (fused); y stored packed bf16; zeros deg
__global__ __launch_bounds__(256) void k_y8(const float* __restrict__ xc,
                                            const float* __restrict__ Wl,
                                            const float* __restrict__ Wr,
                                            const float* __restrict__ Wsh,
                                            const float* __restrict__ Wwt,
                                            int layer,
                                            unsigned* __restrict__ yp01,
                                            unsigned short* __restrict__ yp2,
                                            float* __restrict__ aR, float* __restrict__ aC,
                                            float* __restrict__ wR, float* __restrict__ wC,
                                            float* __restrict__ deg) {
    __shared__ float wrs[32 * 33];
    __shared__ float wls[9];
    __shared__ float xcs[8][96];
    __shared__ float ws1[192], wt[192];
    int tid = threadIdx.x;
    int n0 = blockIdx.x * 8;
    if (tid < 8) { int nz = n0 + tid; if (nz < NN) deg[nz] = 0.0f; }   // consumed by later dispatch
    for (int i = tid; i < 1024; i += 256) wrs[(i >> 5) * 33 + (i & 31)] = Wr[i];
    if (tid < 9) wls[tid] = Wl[tid];
    if (tid < 192) {
        ws1[tid] = Wsh[(layer * 3 + 1) * 192 + tid];  // only row 1 of W_sheaf survives Cayley (D=2)
        wt[tid]  = Wwt[layer * 192 + tid];
    }
    for (int i = tid; i < 768; i += 256) {
        int n = n0 + i / 96;
        xcs[i / 96][i % 96] = (n < NN) ? xc[n * 96 + i % 96] : 0.0f;
    }
    __syncthreads();
    int node = tid >> 5, c = tid & 31;
    int n = n0 + node;
    float a1 = 0, a2 = 0, a3 = 0, a4 = 0;
#pragma unroll
    for (int j = 0; j < 3; ++j) {
        int k = j * 32 + c;
        float xv = xcs[node][k];
        a1 = fmaf(xv, ws1[k], a1);
        a2 = fmaf(xv, ws1[96 + k], a2);
        a3 = fmaf(xv, wt[k], a3);
        a4 = fmaf(xv, wt[96 + k], a4);
    }
#pragma unroll
    for (int off = 16; off; off >>= 1) {
        a1 += __shfl_xor(a1, off);
        a2 += __shfl_xor(a2, off);
        a3 += __shfl_xor(a3, off);
        a4 += __shfl_xor(a4, off);
    }
    if (c == 0 && n < NN) { aR[n] = a1; aC[n] = a2; wR[n] = a3; wC[n] = a4; }
    if (n < NN) {
        float t0 = 0, t1 = 0, t2 = 0;
        const float* wr = &wrs[c * 33];
        const float* xr = xcs[node];
#pragma unroll
        for (int h = 0; h < 32; ++h) {
            float w = wr[h];
            t0 = fmaf(xr[h], w, t0);
            t1 = fmaf(xr[32 + h], w, t1);
            t2 = fmaf(xr[64 + h], w, t2);
        }
        float o0 = wls[0] * t0 + wls[1] * t1 + wls[2] * t2;
        float o1 = wls[3] * t0 + wls[4] * t1 + wls[5] * t2;
        float o2 = wls[6] * t0 + wls[7] * t1 + wls[8] * t2;
        yp01[n * 32 + c] = rne_bf16(o0) | (rne_bf16(o1) << 16);
        yp2[n * 32 + c]  = (unsigned short)rne_bf16(o2);
    }
}

// ---------------- per-edge coefficients (E0 only; reverse via symmetry) + degree
__global__ __launch_bounds__(256) void k_edge_coef(const int* __restrict__ row, const int* __restrict__ col,
                                                   const int* __restrict__ eslot,
                                                   const float* __restrict__ aR, const float* __restrict__ aC,
                                                   const float* __restrict__ wR, const float* __restrict__ wC,
                                                   float4* __restrict__ meta, float* __restrict__ deg) {
    int e = blockIdx.x * 256 + threadIdx.x;
    if (e >= E0) return;
    int u = row[e], v = col[e];
    float a_e = tanhf(aR[u] + aC[v]);
    float a_r = tanhf(aR[v] + aC[u]);
    float wd_e = sigmoidf(wR[u] + wC[v]);
    float wd_r = sigmoidf(wR[v] + wC[u]);
    float w = wd_e * wd_r;
    float w2 = w * w;
    float ie = 1.0f / (1.0f + a_e * a_e), ir = 1.0f / (1.0f + a_r * a_r);
    float ce = (1.0f - a_e * a_e) * ie, se = 2.0f * a_e * ie;
    float cr = (1.0f - a_r * a_r) * ir, sr = 2.0f * a_r * ir;
    float C = ce * cr + se * sr;   // T_e = Q_e^T Q_rev ; T_rev = T_e^T -> (C, -S)
    float S = ce * sr - se * cr;
    meta[eslot[e]]      = make_float4(C,  S, w2, __int_as_float(v));
    meta[eslot[e + E0]] = make_float4(C, -S, w2, __int_as_float(u));
    atomicAdd(&deg[u], w2);
    atomicAdd(&deg[v], w2);
}

__global__ __launch_bounds__(256) void k_dinv(const float* __restrict__ deg, float* __restrict__ dinv) {
    int n = blockIdx.x * 256 + threadIdx.x;
    if (n >= NN) return;
    float d = deg[n];
    dinv[n] = d > 0.0f ? rsqrtf(fmaxf(d, 1e-30f)) : 0.0f;
}

// ---------------- gather + residual update (bf16 y, slot-ordered meta, shfl broadcast)
__global__ __launch_bounds__(256) void k_gather_update(const int* __restrict__ start, const int* __restrict__ cnt,
                                                       const float4* __restrict__ meta,
                                                       const float* __restrict__ dinv,
                                                       const unsigned* __restrict__ yp01,
                                                       const unsigned short* __restrict__ yp2,
                                                       const float* __restrict__ eps,
                                                       int layer, float* __restrict__ xc) {
    int tid = threadIdx.x;
    int node = tid >> 5, c = tid & 31;
    int n = blockIdx.x * 8 + node;
    if (n >= NN) return;
    int s0 = start[n], ec = cnt[n];
    float du = dinv[n];
    float acc0 = 0, acc1 = 0, acc2 = 0;
    for (int bs = 0; bs < ec; bs += 32) {
        int nb = min(32, ec - bs);
        float CC = 0, SS = 0, cnl = 0;
        int vj = 0;
        if (c < nb) {
            float4 mt = meta[s0 + bs + c];
            vj = __float_as_int(mt.w);
            cnl = mt.z * du * dinv[vj];   // parallel per-lane dinv loads (no serial chain)
            CC = cnl * mt.x;
            SS = cnl * mt.y;
        }
        for (int j = 0; j < nb; ++j) {
            float Cj = __shfl(CC, j, 32);
            float Sj = __shfl(SS, j, 32);
            float cj = __shfl(cnl, j, 32);
            int v = __shfl(vj, j, 32);
            unsigned u01 = yp01[v * 32 + c];
            unsigned u2v = (unsigned)yp2[v * 32 + c];
            float y0 = __uint_as_float(u01 << 16);
            float y1 = __uint_as_float(u01 & 0xffff0000u);
            float y2 = __uint_as_float(u2v << 16);
            acc0 = fmaf(Cj, y0, acc0);
            acc0 = fmaf(-Sj, y1, acc0);
            acc1 = fmaf(Sj, y0, acc1);
            acc1 = fmaf(Cj, y1, acc1);
            acc2 = fmaf(cj, y2, acc2);
        }
    }
    float diag = du > 0.0f ? 1.0f : 0.0f;
    unsigned u01 = yp01[n * 32 + c];
    unsigned u2v = (unsigned)yp2[n * 32 + c];
    float oy0 = __uint_as_float(u01 << 16);
    float oy1 = __uint_as_float(u01 & 0xffff0000u);
    float oy2 = __uint_as_float(u2v << 16);
    float c0 = 1.0f + tanhf(eps[layer * 3 + 0]);
    float c1 = 1.0f + tanhf(eps[layer * 3 + 1]);
    float c2 = 1.0f + tanhf(eps[layer * 3 + 2]);
    int base = n * 96 + c;
    float z0 = eluf(diag * oy0 - acc0);
    float z1 = eluf(diag * oy1 - acc1);
    float z2 = eluf(diag * oy2 - acc2);
    xc[base]      = c0 * xc[base]      - z0;
    xc[base + 32] = c1 * xc[base + 32] - z1;
    xc[base + 64] = c2 * xc[base + 64] - z2;
}

extern "C" void kernel_launch(void* const* d_in, const int* in_sizes, int n_in,
                              void* d_out, int out_size, void* d_ws, size_t ws_size,
                              hipStream_t stream) {
    const float* x     = (const float*)d_in[0];
    const int*   ei    = (const int*)d_in[1];
    const float* W1    = (const float*)d_in[2];
    const float* b1    = (const float*)d_in[3];
    const float* W2    = (const float*)d_in[4];
    const float* bias2 = (const float*)d_in[5];
    const float* Wl_in = (const float*)d_in[6];
    const float* Wr_in = (const float*)d_in[7];
    const float* eps   = (const float*)d_in[8];
    const float* Wsh   = (const float*)d_in[9];
    const float* Wwt   = (const float*)d_in[10];
    float* out = (float*)d_out;
    const int* row = ei;        // edge_index[0]
    const int* col = ei + E2;   // edge_index[1]

    char* pc = (char*)d_ws;
    float* xc    = (float*)pc;          pc += (size_t)NN * 96 * 4;
    float4* meta = (float4*)pc;         pc += (size_t)E2 * 16;
    unsigned* yp01 = (unsigned*)pc;     pc += (size_t)NN * 32 * 4;
    unsigned short* yp2 = (unsigned short*)pc; pc += (size_t)NN * 32 * 2;
    float* aR    = (float*)pc;          pc += (size_t)NN * 4;
    float* aC    = (float*)pc;          pc += (size_t)NN * 4;
    float* wRp   = (float*)pc;          pc += (size_t)NN * 4;
    float* wCp   = (float*)pc;          pc += (size_t)NN * 4;
    float* deg   = (float*)pc;          pc += (size_t)NN * 4;
    float* dinv  = (float*)pc;          pc += (size_t)NN * 4;
    float* Wl_n  = (float*)pc;          pc += 32 * 4;
    float* Wr_n  = (float*)pc;          pc += 2048 * 4;
    int* cnt     = (int*)pc;            pc += (size_t)NN * 4;
    int* start   = (int*)pc;            pc += (size_t)NN * 4;
    int* fill    = (int*)pc;            pc += (size_t)NN * 4;
    int* eslot   = (int*)pc;            pc += (size_t)E2 * 4;
    int* bsum    = (int*)pc;            pc += 256 * 4;
    int* bofs    = (int*)pc;            pc += 256 * 4;
    unsigned short* w1hi = (unsigned short*)pc; pc += 96 * 128 * 2;
    unsigned short* w1lo = (unsigned short*)pc; pc += 96 * 128 * 2;
    unsigned short* w2hi = (unsigned short*)pc; pc += 32 * 96 * 2;
    unsigned short* w2lo = (unsigned short*)pc; pc += 32 * 96 * 2;

    const int NB  = (NN + 255) / 256;
    const int EB  = (E2 + 255) / 256;
    const int EB0 = (E0 + 255) / 256;
    const int MB  = (NN + 63) / 64;

    k_splitw<<<(96 * 128 + 255) / 256, 256, 0, stream>>>(W1, 96 * 128, w1hi, w1lo);
    k_splitw<<<(32 * 96 + 255) / 256, 256, 0, stream>>>(W2, 32 * 96, w2hi, w2lo);
    k_gemm_mfma<128, 96, true><<<MB, 256, 0, stream>>>(x, w1hi, w1lo, b1, xc);
    k_spectral<<<2, 64, 0, stream>>>(Wl_in, Wr_in, Wl_n, Wr_n);

    // CSR build (once per call)
    hipMemsetAsync(cnt, 0, NN * sizeof(int), stream);
    hipMemsetAsync(fill, 0, NN * sizeof(int), stream);
    k_hist<<<EB, 256, 0, stream>>>(row, cnt);
    k_scan1<<<NB, 256, 0, stream>>>(cnt, start, bsum);
    k_scan2<<<1, 256, 0, stream>>>(bsum, bofs, NB);
    k_scan3<<<NB, 256, 0, stream>>>(start, bofs);
    k_fill<<<EB, 256, 0, stream>>>(row, start, fill, eslot);

    for (int l = 0; l < 2; ++l) {
        k_y8<<<(NN + 7) / 8, 256, 0, stream>>>(xc, Wl_n + l * 9, Wr_n + l * 1024, Wsh, Wwt, l,
                                               yp01, yp2, aR, aC, wRp, wCp, deg);
        k_edge_coef<<<EB0, 256, 0, stream>>>(row, col, eslot, aR, aC, wRp, wCp, meta, deg);
        k_dinv<<<NB, 256, 0, stream>>>(deg, dinv);
        k_gather_update<<<(NN + 7) / 8, 256, 0, stream>>>(start, cnt, meta, dinv,
                                                          yp01, yp2, eps, l, xc);
    }
    k_gemm_mfma<96, 32, false><<<MB, 256, 0, stream>>>(xc, w2hi, w2lo, bias2, out);
}